// Round 5
// baseline (254.268 us; speedup 1.0000x reference)
//
#include <hip/hip_runtime.h>
#include <hip/hip_bf16.h>
#include <stdint.h>

// Problem constants
#define BATCH 4
#define SEQ   4096
#define HID   1024
#define NH    16
#define HD    64
#define CS    16
#define NCH   256          // SEQ/CS
#define MROWS 16384        // BATCH*SEQ

typedef __attribute__((ext_vector_type(8))) __bf16 bf16x8;
typedef __attribute__((ext_vector_type(4))) float  f32x4;
typedef __attribute__((ext_vector_type(8))) unsigned short u16x8;

__device__ __forceinline__ unsigned short f2bf(float f) {
    union { float f; unsigned u; } x; x.f = f;
    unsigned r = x.u + 0x7FFFu + ((x.u >> 16) & 1u);   // RNE
    return (unsigned short)(r >> 16);
}
__device__ __forceinline__ float bf2f(unsigned short v) {
    union { unsigned u; float f; } x; x.u = ((unsigned)v) << 16;
    return x.f;
}

__device__ __forceinline__ void async_copy16(void* lds, const void* g) {
    __builtin_amdgcn_global_load_lds(
        (const __attribute__((address_space(1))) unsigned int*)g,
        (__attribute__((address_space(3))) unsigned int*)lds,
        16, 0, 0);
}

// ---------------------------------------------------------------- convert (all inputs, one kernel)
// 8 floats/thread: 2x float4 loads, 1x 16B ushort8 store
__global__ __launch_bounds__(256) void convert_all_kernel(
    const float* __restrict__ x, const float* __restrict__ W_in,
    const float* __restrict__ W_out, const float* __restrict__ W_gate,
    unsigned short* __restrict__ xb, unsigned short* __restrict__ Wib,
    unsigned short* __restrict__ Wob, unsigned short* __restrict__ Wgb)
{
    int i = blockIdx.x * 256 + threadIdx.x;        // unit = 8 floats
    const float4* src; u16x8* dst; int j;
    if (i < 2097152)      { src = (const float4*)x;      dst = (u16x8*)xb;  j = i; }
    else if (i < 2228224) { src = (const float4*)W_in;   dst = (u16x8*)Wib; j = i - 2097152; }
    else if (i < 2359296) { src = (const float4*)W_out;  dst = (u16x8*)Wob; j = i - 2228224; }
    else if (i < 2363392) { src = (const float4*)W_gate; dst = (u16x8*)Wgb; j = i - 2359296; }
    else return;
    float4 a = src[2 * j], b = src[2 * j + 1];
    u16x8 o;
    o[0] = f2bf(a.x); o[1] = f2bf(a.y); o[2] = f2bf(a.z); o[3] = f2bf(a.w);
    o[4] = f2bf(b.x); o[5] = f2bf(b.y); o[6] = f2bf(b.z); o[7] = f2bf(b.w);
    dst[j] = o;
}

// ---------------------------------------------------------------- GEMM (C = A @ B^T), bf16 in, fp32 out
// 128x128 tile, BK=64, 4 waves (2x2 of 64x64), XOR-swizzled LDS
// (round-0 proven version: 42.2 us, 814 TF on this problem — do not touch)
__global__ __launch_bounds__(256, 2) void gemm_bt_kernel(
    const unsigned short* __restrict__ A,
    const unsigned short* __restrict__ Bm,
    float* __restrict__ C, int M, int N, int K)
{
    __shared__ unsigned short As[128 * 64];
    __shared__ unsigned short Bs[128 * 64];
    const int t = threadIdx.x;
    const int lane = t & 63, w = t >> 6;
    const int wm = w >> 1, wn = w & 1;
    const size_t bm = (size_t)blockIdx.x * 128;
    const size_t bn = (size_t)blockIdx.y * 128;

    f32x4 acc[4][4];
#pragma unroll
    for (int x = 0; x < 4; x++)
#pragma unroll
        for (int y = 0; y < 4; y++)
            acc[x][y] = (f32x4){0.f, 0.f, 0.f, 0.f};

    const int srow = lane >> 3;
    const int gc   = (lane & 7) ^ (srow & 7);      // swizzled global chunk
    const int scol = gc * 8;
    const unsigned short* Ag = A + (bm + w * 32 + srow) * (size_t)K + scol;
    const unsigned short* Bg = Bm + (bn + w * 32 + srow) * (size_t)K + scol;
    unsigned short* Al = As + (w * 32 + srow) * 64 + (lane & 7) * 8;
    unsigned short* Bl = Bs + (w * 32 + srow) * 64 + (lane & 7) * 8;

    const int fr = lane & 15, fq = lane >> 4;
    const int rl = fr & 7;

    for (int k0 = 0; k0 < K; k0 += 64) {
#pragma unroll
        for (int r = 0; r < 4; r++) {
            async_copy16(Al + r * 8 * 64, Ag + (size_t)r * 8 * K + k0);
            async_copy16(Bl + r * 8 * 64, Bg + (size_t)r * 8 * K + k0);
        }
        __syncthreads();
#pragma unroll
        for (int kk = 0; kk < 64; kk += 32) {
            const int c = (kk >> 3) + fq;
            const int pc = c ^ rl;
            bf16x8 af[4], bfv[4];
#pragma unroll
            for (int x = 0; x < 4; x++) {
                af[x]  = *(const bf16x8*)(As + (wm * 64 + x * 16 + fr) * 64 + pc * 8);
                bfv[x] = *(const bf16x8*)(Bs + (wn * 64 + x * 16 + fr) * 64 + pc * 8);
            }
#pragma unroll
            for (int x = 0; x < 4; x++)
#pragma unroll
                for (int y = 0; y < 4; y++)
                    acc[x][y] = __builtin_amdgcn_mfma_f32_16x16x32_bf16(af[x], bfv[y], acc[x][y], 0, 0, 0);
        }
        __syncthreads();
    }

#pragma unroll
    for (int x = 0; x < 4; x++) {
#pragma unroll
        for (int y = 0; y < 4; y++) {
            size_t r0 = bm + wm * 64 + x * 16 + fq * 4;
            size_t c  = bn + wn * 64 + y * 16 + fr;
#pragma unroll
            for (int rg = 0; rg < 4; rg++)
                C[(r0 + rg) * (size_t)N + c] = acc[x][y][rg];
        }
    }
}

// ---------------------------------------------------------------- LN: one wave per row, no LDS, no barriers
__global__ __launch_bounds__(256) void ln_kernel(
    const float* __restrict__ xp, const float* __restrict__ ln_g,
    const float* __restrict__ ln_b, unsigned short* __restrict__ xln)
{
    const int row  = blockIdx.x * 4 + (threadIdx.x >> 6);
    const int lane = threadIdx.x & 63;
    const float* rp = xp + (size_t)row * 1024;
    float4 va[2], vb[2];
    float s = 0.f, s2 = 0.f;
#pragma unroll
    for (int i = 0; i < 2; i++) {
        const int k = lane * 8 + i * 512;
        va[i] = *(const float4*)(rp + k);
        vb[i] = *(const float4*)(rp + k + 4);
        s  += va[i].x + va[i].y + va[i].z + va[i].w
            + vb[i].x + vb[i].y + vb[i].z + vb[i].w;
        s2 += va[i].x * va[i].x + va[i].y * va[i].y + va[i].z * va[i].z + va[i].w * va[i].w
            + vb[i].x * vb[i].x + vb[i].y * vb[i].y + vb[i].z * vb[i].z + vb[i].w * vb[i].w;
    }
#pragma unroll
    for (int off = 1; off < 64; off <<= 1) {
        s  += __shfl_xor(s, off, 64);
        s2 += __shfl_xor(s2, off, 64);
    }
    const float mu  = s * (1.f / 1024.f);
    const float var = s2 * (1.f / 1024.f) - mu * mu;
    const float sc  = rsqrtf(var + 1e-5f);
    unsigned short* orow = xln + (size_t)row * 1024;
#pragma unroll
    for (int i = 0; i < 2; i++) {
        const int k = lane * 8 + i * 512;
        float4 g4a = *(const float4*)(ln_g + k);
        float4 g4b = *(const float4*)(ln_g + k + 4);
        float4 b4a = *(const float4*)(ln_b + k);
        float4 b4b = *(const float4*)(ln_b + k + 4);
        u16x8 o;
        o[0] = f2bf((va[i].x - mu) * sc * g4a.x + b4a.x);
        o[1] = f2bf((va[i].y - mu) * sc * g4a.y + b4a.y);
        o[2] = f2bf((va[i].z - mu) * sc * g4a.z + b4a.z);
        o[3] = f2bf((va[i].w - mu) * sc * g4a.w + b4a.w);
        o[4] = f2bf((vb[i].x - mu) * sc * g4b.x + b4b.x);
        o[5] = f2bf((vb[i].y - mu) * sc * g4b.y + b4b.y);
        o[6] = f2bf((vb[i].z - mu) * sc * g4b.z + b4b.z);
        o[7] = f2bf((vb[i].w - mu) * sc * g4b.w + b4b.w);
        *(u16x8*)(orow + k) = o;
    }
}

// ---------------------------------------------------------------- gates: MFMA gates + cumprod + hc15 (reads bf16 xln)
__global__ __launch_bounds__(256) void gates_kernel(
    const unsigned short* __restrict__ xln,
    const unsigned short* __restrict__ Wgb,   // bf16 [32][1024]
    const float* __restrict__ bg, const float* __restrict__ eig_raw,
    float* __restrict__ beta_buf,             // out: [MROWS][16]
    float* __restrict__ cum_out,              // out: [1024][16][16]
    float* __restrict__ c15c,                 // out: [1024][16]
    float* __restrict__ hc15)                 // out: [1024][1024]
{
    __shared__ unsigned short sx[16][1032];   // 33KB, +8 pad
    __shared__ float red[4][2][64][4];        // 8KB partial gate accs
    __shared__ float sg[16][32];
    __shared__ float scum[16][16];
    const int t = threadIdx.x, lane = t & 63, w = t >> 6;
    const int bn = blockIdx.x;
    const size_t m0 = (size_t)(bn >> 8) * SEQ + (size_t)(bn & 255) * 16;
    const int r = t >> 4, u = t & 15;

    // ---- fill LDS with the chunk's 16 rows of xln (32KB)
    {
        const unsigned short* xrow = xln + (m0 + r) * 1024;
#pragma unroll
        for (int i = 0; i < 8; i++) {
            const int k = u * 8 + i * 128;
            *(u16x8*)&sx[r][k] = *(const u16x8*)(xrow + k);
        }
    }
    __syncthreads();

    // ---- gates via MFMA: wave w covers K in [w*256,(w+1)*256)
    const int fr = lane & 15, fq = lane >> 4;
    {
        f32x4 acc0 = (f32x4){0.f,0.f,0.f,0.f}, acc1 = (f32x4){0.f,0.f,0.f,0.f};
        const unsigned short* Wr0 = Wgb + (size_t)fr * 1024;
        const unsigned short* Wr1 = Wgb + (size_t)(16 + fr) * 1024;
#pragma unroll
        for (int ks = 0; ks < 8; ks++) {
            const int k0 = w * 256 + ks * 32 + fq * 8;
            bf16x8 af = *(const bf16x8*)&sx[fr][k0];
            bf16x8 b0 = *(const bf16x8*)(Wr0 + k0);
            bf16x8 b1 = *(const bf16x8*)(Wr1 + k0);
            acc0 = __builtin_amdgcn_mfma_f32_16x16x32_bf16(af, b0, acc0, 0, 0, 0);
            acc1 = __builtin_amdgcn_mfma_f32_16x16x32_bf16(af, b1, acc1, 0, 0, 0);
        }
        *(f32x4*)&red[w][0][lane][0] = acc0;
        *(f32x4*)&red[w][1][lane][0] = acc1;
    }
    __syncthreads();
    if (t < 128) {
        const int y = t >> 6, l = t & 63;
        f32x4 s = *(const f32x4*)&red[0][y][l][0];
#pragma unroll
        for (int ww = 1; ww < 4; ww++) {
            f32x4 p = *(const f32x4*)&red[ww][y][l][0];
            s[0] += p[0]; s[1] += p[1]; s[2] += p[2]; s[3] += p[3];
        }
        const int col = y * 16 + (l & 15);
        const int row0 = (l >> 4) * 4;
        const float bias = bg[col];
#pragma unroll
        for (int rg = 0; rg < 4; rg++)
            sg[row0 + rg][col] = 1.f / (1.f + expf(-(s[rg] + bias)));
    }
    __syncthreads();

    // ---- cumprod of a = tanh(eig)*alpha
    if (t < 16) {
        const float ev = tanhf(eig_raw[t]);
        float c = 1.f;
#pragma unroll
        for (int i = 0; i < 16; i++) { c *= ev * sg[i][t]; scum[i][t] = c; }
    }
    // beta out
    beta_buf[(m0 + r) * 16 + u] = sg[r][16 + u];
    __syncthreads();

    // cum/c15 out
    cum_out[(size_t)bn * 256 + t] = scum[t >> 4][t & 15];
    if (t < 16) c15c[bn * 16 + t] = scum[15][t];

    // ---- hc15 via prefix form: hc15 = cum15 * sum_{j<15} bb[j]/cpad[j] + bb[15]
    {
        const int h = t >> 4, d0 = (t & 15) * 4;
        float s0 = 0.f, s1 = 0.f, s2 = 0.f, s3 = 0.f;
        float b0 = 0.f, b1 = 0.f, b2 = 0.f, b3 = 0.f;
        float cprev = 1.f;
#pragma unroll
        for (int j = 0; j < 16; j++) {
            const float bt = sg[j][16 + h];
            ushort4 xv = *(const ushort4*)&sx[j][h * 64 + d0];
            b0 = bt * bf2f(xv.x); b1 = bt * bf2f(xv.y);
            b2 = bt * bf2f(xv.z); b3 = bt * bf2f(xv.w);
            if (j < 15) {
                const float inv = (fabsf(cprev) > 1e-8f) ? (1.f / cprev) : 0.f;
                s0 += b0 * inv; s1 += b1 * inv; s2 += b2 * inv; s3 += b3 * inv;
                cprev = scum[j][h];
            }
        }
        const float c15 = scum[15][h];
        float4 o = { c15 * s0 + b0, c15 * s1 + b1, c15 * s2 + b2, c15 * s3 + b3 };
        *(float4*)(hc15 + (size_t)bn * 1024 + h * 64 + d0) = o;
    }
}

// ---------------------------------------------------------------- hierarchical inter-chunk scan
// Level A: compose 16-chunk groups into affine (P,S).
__global__ __launch_bounds__(256) void scan2a_kernel(
    const float* __restrict__ c15c,      // [1024][16]
    const float* __restrict__ hc15,      // [1024][1024]
    float* __restrict__ Pg,              // [4][16][1024]
    float* __restrict__ Sg)              // [4][16][1024]
{
    const int tid = blockIdx.x * 256 + threadIdx.x;      // 0..65535
    const int b = tid >> 14, g = (tid >> 10) & 15, hd = tid & 1023, h = hd >> 6;
    const int n0 = b * NCH + g * 16;
    float P = 1.f, S = 0.f;
#pragma unroll
    for (int j = 0; j < 16; j++) {
        const float c = c15c[(n0 + j) * 16 + h];
        S = c * S + hc15[(size_t)(n0 + j) * 1024 + hd];
        P = c * P;
    }
    Pg[tid] = P;
    Sg[tid] = S;
}

// ---------------------------------------------------------------- scan3 (fused carry reconstruction + intra-chunk)
// Each block rebuilds its chunk's carry from L2-resident Pg/Sg (group
// prefix, <=15 steps) + c15c/hc15 (within-group prefix, <=15 steps),
// then runs the register-resident intra-chunk pass. n==255 block emits
// h_final. Eliminates scan2c launch + carry_in round-trip.
__global__ __launch_bounds__(128) void scan3_kernel(
    const float* __restrict__ cum_buf,
    const float* __restrict__ beta_buf,
    const unsigned short* __restrict__ xln,
    const float* __restrict__ c15c,
    const float* __restrict__ hc15,
    const float* __restrict__ Pg,
    const float* __restrict__ Sg,
    unsigned short* __restrict__ hall,          // [MROWS][1024] bf16
    float* __restrict__ h_final)                // [4][1024]
{
    __shared__ float scum[16][16];
    __shared__ float sbeta[16][16];
    const int t = threadIdx.x;                  // 0..127
    const int bn = blockIdx.x;
    const int b = bn >> 8, n = bn & 255, g = n >> 4;
    const size_t m0 = (size_t)b * SEQ + (size_t)n * 16;

    {
        const int i0 = t, i1 = t + 128;
        scum[i0 >> 4][i0 & 15]  = cum_buf[(size_t)bn * 256 + i0];
        scum[i1 >> 4][i1 & 15]  = cum_buf[(size_t)bn * 256 + i1];
        sbeta[i0 >> 4][i0 & 15] = beta_buf[(m0 + (i0 >> 4)) * 16 + (i0 & 15)];
        sbeta[i1 >> 4][i1 & 15] = beta_buf[(m0 + (i1 >> 4)) * 16 + (i1 & 15)];
    }
    __syncthreads();

    const int h = t >> 3, dq = t & 7;
    const size_t off = h * 64 + dq * 8;

    // ---- carry reconstruction
    float s[8];
#pragma unroll
    for (int e = 0; e < 8; e++) s[e] = 0.f;
    for (int gp = 0; gp < g; gp++) {             // wave-uniform trip count
        const size_t idx = ((size_t)(b * 16 + gp) << 10) + off;
        float4 p0 = *(const float4*)(Pg + idx), p1 = *(const float4*)(Pg + idx + 4);
        float4 q0 = *(const float4*)(Sg + idx), q1 = *(const float4*)(Sg + idx + 4);
        s[0] = p0.x * s[0] + q0.x; s[1] = p0.y * s[1] + q0.y;
        s[2] = p0.z * s[2] + q0.z; s[3] = p0.w * s[3] + q0.w;
        s[4] = p1.x * s[4] + q1.x; s[5] = p1.y * s[5] + q1.y;
        s[6] = p1.z * s[6] + q1.z; s[7] = p1.w * s[7] + q1.w;
    }
    for (int jj = (g << 4); jj < n; jj++) {      // wave-uniform trip count
        const size_t cn = (size_t)b * 256 + jj;
        const float c = c15c[cn * 16 + h];
        float4 h0 = *(const float4*)(hc15 + cn * 1024 + off);
        float4 h1 = *(const float4*)(hc15 + cn * 1024 + off + 4);
        s[0] = c * s[0] + h0.x; s[1] = c * s[1] + h0.y;
        s[2] = c * s[2] + h0.z; s[3] = c * s[3] + h0.w;
        s[4] = c * s[4] + h1.x; s[5] = c * s[5] + h1.y;
        s[6] = c * s[6] + h1.z; s[7] = c * s[7] + h1.w;
    }
    if (n == 255) {
        const size_t cn = (size_t)b * 256 + 255;
        const float c = c15c[cn * 16 + h];
        float4 h0 = *(const float4*)(hc15 + cn * 1024 + off);
        float4 h1 = *(const float4*)(hc15 + cn * 1024 + off + 4);
        float4 f0 = { c * s[0] + h0.x, c * s[1] + h0.y, c * s[2] + h0.z, c * s[3] + h0.w };
        float4 f1 = { c * s[4] + h1.x, c * s[5] + h1.y, c * s[6] + h1.z, c * s[7] + h1.w };
        *(float4*)(h_final + ((size_t)b << 10) + off)     = f0;
        *(float4*)(h_final + ((size_t)b << 10) + off + 4) = f1;
    }

    // ---- intra-chunk prefix pass
    float cprev = 1.f;
#pragma unroll
    for (int i = 0; i < 16; i++) {
        u16x8 xv = *(const u16x8*)(xln + (m0 + i) * 1024 + off);
        const float bt = sbeta[i][h];
        const float ci = scum[i][h];
        float bb[8];
        u16x8 o;
#pragma unroll
        for (int e = 0; e < 8; e++) {
            bb[e] = bt * bf2f(xv[e]);
            o[e] = f2bf(ci * s[e] + bb[e]);
        }
        *(u16x8*)(hall + (m0 + i) * 1024 + off) = o;
        const float inv = (fabsf(cprev) > 1e-8f) ? (1.f / cprev) : 0.f;
#pragma unroll
        for (int e = 0; e < 8; e++)
            s[e] += bb[e] * inv;
        cprev = ci;
    }
}

// ---------------------------------------------------------------- launch
extern "C" void kernel_launch(void* const* d_in, const int* in_sizes, int n_in,
                              void* d_out, int out_size, void* d_ws, size_t ws_size,
                              hipStream_t stream)
{
    const float* x       = (const float*)d_in[0];
    const float* W_in    = (const float*)d_in[1];
    const float* ln_g    = (const float*)d_in[2];
    const float* ln_b    = (const float*)d_in[3];
    const float* W_gate  = (const float*)d_in[4];
    const float* b_gate  = (const float*)d_in[5];
    const float* eig_raw = (const float*)d_in[6];
    const float* W_out   = (const float*)d_in[7];
    float* out = (float*)d_out;

    char* ws = (char*)d_ws;
    unsigned short* xb   = (unsigned short*)(ws);                   // 32MB; reused as xln after gemm1
    unsigned short* xln  = (unsigned short*)(ws);
    unsigned short* hall = (unsigned short*)(ws + 33554432);        // 32MB
    unsigned short* Wib  = (unsigned short*)(ws + 67108864);        // 2MB
    unsigned short* Wob  = (unsigned short*)(ws + 69206016);        // 2MB
    unsigned short* Wgb  = (unsigned short*)(ws + 71303168);        // 64KB
    float* beta_buf = (float*)(ws + 71368704);                      // 1MB
    float* cum_buf  = (float*)(ws + 72417280);                      // 1MB
    float* c15c     = (float*)(ws + 73465856);                      // 64KB
    float* hc15     = (float*)(ws + 73531392);                      // 4MB
    // Pg/Sg live in the old carry_in slot (must NOT alias hall: scan3
    // writes hall while reading Pg/Sg)
    float* Pg = (float*)(ws + 77725696);                            // 256KB
    float* Sg = (float*)(ws + 77725696 + 262144);                   // 256KB (end ~78.2MB)

    float* xp = out;                       // d_out head doubles as xp scratch
    float* h_final = out + 16777216;

    convert_all_kernel<<<9232, 256, 0, stream>>>(x, W_in, W_out, W_gate, xb, Wib, Wob, Wgb);

    dim3 gg(128, 8);
    gemm_bt_kernel<<<gg, 256, 0, stream>>>(xb, Wib, xp, MROWS, HID, HID);

    ln_kernel<<<4096, 256, 0, stream>>>(xp, ln_g, ln_b, xln);

    gates_kernel<<<1024, 256, 0, stream>>>(xln, Wgb, b_gate, eig_raw,
                                           beta_buf, cum_buf, c15c, hc15);

    scan2a_kernel<<<256, 256, 0, stream>>>(c15c, hc15, Pg, Sg);

    scan3_kernel<<<1024, 128, 0, stream>>>(cum_buf, beta_buf, xln, c15c, hc15,
                                           Pg, Sg, hall, h_final);

    gemm_bt_kernel<<<gg, 256, 0, stream>>>(hall, Wob, out, MROWS, HID, HID);
}